// Round 13
// baseline (419.731 us; speedup 1.0000x reference)
//
#include <hip/hip_runtime.h>

// CRF Viterbi decode (B=512, T=512, S=64).
// R12: BARRIER-FREE single wave per batch (512 blocks x 64 thr). No
// cross-wave exchange at all -- the 3 multi-wave structures (R3/R9/R11)
// all plateau at ~1320 cyc/step on barrier+LDS rendezvous at 2 waves/SIMD
// (grid caps waves/CU at 8, so rendezvous latency can't be hidden).
// Per step, entirely in-wave:
//   gather: 64 LITERAL-lane v_readlane of fv + 64 adds vs in-register
//           trans row (validated clean in R1 -- no waterfall);
//   reduce: balanced carry-index tree -- 8 sub-trees of 8 + 7-node final
//           merge (63 nodes x ~3 instr, depth 6), strict >, left-on-tie
//           everywhere = exact jnp first-argmax (validated R1-R11);
//   prefetch: emissions+masks in groups of 4 steps, 2 groups deep
//           (validated R9) -> 8-12 steps (~5000+ cyc) of lookahead, covers
//           the ~900-cyc HBM latency that stalled R1's depth-1 scheme.
// Backpointers packed 4 tags/dword in LDS (32 KB); backtrace = validated
// readlane chain. Output: out[0..B) = path_score,
// out[B + b*(T-1) + t] = (float)tag.

constexpr int Bz = 512;
constexpr int Tz = 512;
constexpr int Sz = 64;
constexpr float NEGINF = -10000.0f;

__device__ __forceinline__ float rlf(float x, int lane) {
    return __int_as_float(__builtin_amdgcn_readlane(__float_as_int(x), lane));
}

__global__ __launch_bounds__(64)
void crf_viterbi_kernel(const float* __restrict__ logits,
                        const float* __restrict__ masks,
                        const float* __restrict__ trans,
                        float* __restrict__ out)
{
    const int n = threadIdx.x & 63;   // lane id = next-tag
    const int b = blockIdx.x;

    __shared__ unsigned bp[128 * 64]; // packed backpointers, 32 KB
    __shared__ float ys[Tz - 1];      // emitted tags (backtrace)

    // full transitions row for this tag: tr[p] = trans[n][p]
    float tr[64];
    {
        const float4* tr4 = reinterpret_cast<const float4*>(trans + n * 64);
        #pragma unroll
        for (int k = 0; k < 16; ++k) {
            float4 t = tr4[k];
            tr[4 * k + 0] = t.x; tr[4 * k + 1] = t.y;
            tr[4 * k + 2] = t.z; tr[4 * k + 3] = t.w;
        }
    }

    float fv = (n == 0) ? 0.0f : NEGINF;

    const float* lgbase = logits + (size_t)b * Tz * Sz;
    const float* mkbase = masks + (size_t)b * Tz;

    // group-of-4 prefetch, 2 groups deep (validated R9 scheme)
    float lgc[4], lgn[4], mkc[4], mkn[4];
    #pragma unroll
    for (int k = 0; k < 4; ++k) {
        lgc[k] = lgbase[(1 + k) * Sz + n];  mkc[k] = mkbase[1 + k];
        lgn[k] = lgbase[(5 + k) * Sz + n];  mkn[k] = mkbase[5 + k];
    }

    unsigned pk = 0;
    float psc = 0.0f;

    // one Viterbi step (k compile-time); returns pre-feat max
    auto step = [&](int k, float lg, float mk) -> float {
        // 8 sub-trees of 8 (literal lanes; <=8 v[] live at once)
        float mv[8]; int mi[8];
        #pragma unroll
        for (int c = 0; c < 8; ++c) {
            float v[8];
            #pragma unroll
            for (int j = 0; j < 8; ++j)
                v[j] = rlf(fv, 8 * c + j) + tr[8 * c + j];
            // balanced carry-index tree of 8 (depth 3)
            float a0, a1, a2, a3; int i0, i1, i2, i3;
            {
                bool g;
                g = v[1] > v[0]; a0 = g ? v[1] : v[0]; i0 = g ? (8*c+1) : (8*c+0);
                g = v[3] > v[2]; a1 = g ? v[3] : v[2]; i1 = g ? (8*c+3) : (8*c+2);
                g = v[5] > v[4]; a2 = g ? v[5] : v[4]; i2 = g ? (8*c+5) : (8*c+4);
                g = v[7] > v[6]; a3 = g ? v[7] : v[6]; i3 = g ? (8*c+7) : (8*c+6);
            }
            bool g01 = a1 > a0;  float b0 = g01 ? a1 : a0;  int j0 = g01 ? i1 : i0;
            bool g23 = a3 > a2;  float b1 = g23 ? a3 : a2;  int j1 = g23 ? i3 : i2;
            bool gb  = b1 > b0;
            mv[c] = gb ? b1 : b0;
            mi[c] = gb ? j1 : j0;
        }
        // final balanced merge over 8 sub-trees (depth 3, ascending order)
        #pragma unroll
        for (int st = 1; st < 8; st <<= 1) {
            #pragma unroll
            for (int c = 0; c < 8; c += 2 * st) {
                bool g = mv[c + st] > mv[c];
                mv[c] = g ? mv[c + st] : mv[c];
                mi[c] = g ? mi[c + st] : mi[c];
            }
        }
        float m = mv[0];
        pk |= ((unsigned)mi[0]) << (8 * k);
        fv = m + lg * mk;                 // mask multiplies emission only
        return m;
    };

    // main: groups g = 0..126 cover steps i = 4g+k (i <= 507)
    for (int g = 0; g < 127; ++g) {
        step(0, lgc[0], mkc[0]);
        step(1, lgc[1], mkc[1]);
        step(2, lgc[2], mkc[2]);
        step(3, lgc[3], mkc[3]);

        bp[g * 64 + n] = pk;
        pk = 0;

        // rotate prefetch; issue loads for group g+2 (rows 4g+9 .. 4g+12)
        #pragma unroll
        for (int k = 0; k < 4; ++k) { lgc[k] = lgn[k]; mkc[k] = mkn[k]; }
        #pragma unroll
        for (int k = 0; k < 4; ++k) {
            int t = 4 * g + 9 + k;
            t = (t < Tz) ? t : (Tz - 1);
            lgn[k] = lgbase[t * Sz + n];
            mkn[k] = mkbase[t];
        }
    }

    // tail: steps 508 (k0), 509 (k1), 510 (k2); i=510 == Tz-2 -> path_score
    step(0, lgc[0], mkc[0]);
    step(1, lgc[1], mkc[1]);
    psc = step(2, lgc[2], mkc[2]);        // vmaxs[-1] pre-feat

    bp[127 * 64 + n] = pk;                // flush steps 508..510
    if (n == 63) out[b] = psc;            // path_score = vmaxs[-1][:,63]

    __syncthreads();

    // ---- backtrace (validated readlane chain, single wave) ----
    {
        unsigned wcur = bp[127 * 64 + n];
        int w127_63 = __builtin_amdgcn_readlane((int)wcur, 63);
        int tag = (w127_63 >> 16) & 255;  // t0 = bptrs[510][63]

        for (int g = 127; g >= 0; --g) {
            unsigned wnext = (g > 0) ? bp[(g - 1) * 64 + n] : 0u;  // prefetch
            int smax = (g == 127) ? 2 : 3;
            for (int s = smax; s >= 0; --s) {
                int idx = 4 * g + s;
                if (n == 0) ys[idx] = (float)tag;   // emit BEFORE following ptr
                int wd = __builtin_amdgcn_readlane((int)wcur, tag);
                tag = (wd >> (8 * s)) & 255;
            }
            wcur = wnext;
        }
    }

    __syncthreads();

    float* outseq = out + Bz + (size_t)b * (Tz - 1);
    for (int k = n; k < Tz - 1; k += 64) outseq[k] = ys[k];
}

extern "C" void kernel_launch(void* const* d_in, const int* in_sizes, int n_in,
                              void* d_out, int out_size, void* d_ws, size_t ws_size,
                              hipStream_t stream) {
    const float* logits = (const float*)d_in[0];
    const float* masks  = (const float*)d_in[1];
    const float* trans  = (const float*)d_in[2];
    float* out = (float*)d_out;
    (void)in_sizes; (void)n_in; (void)out_size; (void)d_ws; (void)ws_size;

    crf_viterbi_kernel<<<dim3(Bz), dim3(64), 0, stream>>>(logits, masks, trans, out);
}